// Round 4
// baseline (240.010 us; speedup 1.0000x reference)
//
#include <hip/hip_runtime.h>
#include <hip/hip_fp16.h>

#define N_ROWS 1024
#define DIM 256
#define HID 512
#define NB 256
#define NT 256

typedef _Float16 half_t;
typedef __attribute__((ext_vector_type(4))) _Float16 half4v;
typedef __attribute__((ext_vector_type(8))) _Float16 half8v;
typedef __attribute__((ext_vector_type(16))) float f32x16;

struct Params {
    const float* a;
    const float* b;
    const float* w[6];      // w0m,w0l,w1m,w1l,w2m,w2l (fp32, K x N)
    const float* bias[6];   // b0m,b0l,b1m,b1l,b2m,b2l
    unsigned* bar;          // 4 counters at stride 32 uints (zeroed per call)
    float* acc;             // zeroed per call
    unsigned* done;         // zeroed per call
    float* part_s;          // [64][256]
    float* part_s2;         // [64][256]
    float* mu_raw;          // [1024][256] f32
    float* lv_raw;          // [1024][256] f32
    half_t* a16;            // [1024][256]
    half_t* wt[6];          // transposed f16 weights (N x K)
    half_t* h1m; half_t* h1l;   // [1024][512]
    half_t* h2m; half_t* h2l;   // [1024][512]
    float* out;
};

// device-wide barrier: one counter per barrier, never reset within a call.
__device__ __forceinline__ void gsync(unsigned* ctr) {
    __syncthreads();
    __threadfence();                      // release: flush our writes device-wide
    if (threadIdx.x == 0) {
        __hip_atomic_fetch_add(ctr, 1u, __ATOMIC_RELAXED, __HIP_MEMORY_SCOPE_AGENT);
        while (__hip_atomic_load(ctr, __ATOMIC_RELAXED, __HIP_MEMORY_SCOPE_AGENT) < (unsigned)NB)
            __builtin_amdgcn_s_sleep(2);
    }
    __syncthreads();
    __threadfence();                      // acquire: invalidate stale cache lines
}

// ---- 64x64 MFMA GEMM tile (round-3 validated structure) ----
// A: M x K f16 row-major; Wt: N x K f16; C = act(A@Wt^T + bias)
__device__ __forceinline__ void gemm_tile(const half_t* __restrict__ A,
                                          const half_t* __restrict__ Wt,
                                          const float* __restrict__ bias,
                                          void* __restrict__ Cp,
                                          const int K, const int Nout,
                                          const int bm, const int bn,
                                          const bool relu, const bool out16,
                                          char* smemraw) {
    typedef half_t(*lds_t)[64][40];
    lds_t As = (lds_t)smemraw;                       // [2][64][40] f16
    lds_t Bs = (lds_t)(smemraw + 2 * 64 * 40 * 2);

    const int tid = threadIdx.x;
    const int sr = tid >> 2, sg = (tid & 3) * 8;
    const int wave = tid >> 6, lane = tid & 63;
    const int wr = (wave >> 1) * 32, wc = (wave & 1) * 32;
    const int lr = lane & 31, hi = lane >> 5;

    f32x16 acc;
    #pragma unroll
    for (int i = 0; i < 16; ++i) acc[i] = 0.f;

    const half_t* aP = &A[(bm + sr) * K + sg];
    const half_t* bP = &Wt[(bn + sr) * K + sg];
    const int NC = K >> 5;

    float4 aR = *(const float4*)aP;
    float4 bR = *(const float4*)bP;
    *(float4*)&As[0][sr][sg] = aR;
    *(float4*)&Bs[0][sr][sg] = bR;
    __syncthreads();

    for (int c = 0; c < NC; ++c) {
        const int cur = c & 1;
        const bool more = (c + 1 < NC);
        if (more) {
            aR = *(const float4*)(aP + (c + 1) * 32);
            bR = *(const float4*)(bP + (c + 1) * 32);
        }
        half8v av0 = *(const half8v*)&As[cur][wr + lr][hi * 8];
        half8v bv0 = *(const half8v*)&Bs[cur][wc + lr][hi * 8];
        acc = __builtin_amdgcn_mfma_f32_32x32x16_f16(av0, bv0, acc, 0, 0, 0);
        half8v av1 = *(const half8v*)&As[cur][wr + lr][hi * 8 + 16];
        half8v bv1 = *(const half8v*)&Bs[cur][wc + lr][hi * 8 + 16];
        acc = __builtin_amdgcn_mfma_f32_32x32x16_f16(av1, bv1, acc, 0, 0, 0);
        __syncthreads();
        if (more) {
            const int nxt = cur ^ 1;
            *(float4*)&As[nxt][sr][sg] = aR;
            *(float4*)&Bs[nxt][sr][sg] = bR;
            __syncthreads();
        }
    }

    // C/D layout: col = lane&31, row = (reg&3) + 8*(reg>>2) + 4*(lane>>5)
    const int col = bn + wc + lr;
    const float bv = bias[col];
    const int rbase = bm + wr + 4 * hi;
    #pragma unroll
    for (int r = 0; r < 16; ++r) {
        int row = rbase + (r & 3) + 8 * (r >> 2);
        float v = acc[r] + bv;
        if (relu) v = fmaxf(v, 0.f);
        if (out16) ((half_t*)Cp)[row * Nout + col] = (half_t)v;
        else       ((float*)Cp)[row * Nout + col] = v;
    }
}

__global__ void __launch_bounds__(NT) fused_kernel(Params p) {
    __shared__ alignas(16) char smem[20480];
    const int bid = blockIdx.x, tid = threadIdx.x;

    // ================= phase 0: prep =================
    {   // domain_a fp32 -> f16 (1024 els/block)
        int base = bid * 1024 + tid * 4;
        float4 v = *(const float4*)&p.a[base];
        half4v h;
        h[0] = (half_t)v.x; h[1] = (half_t)v.y; h[2] = (half_t)v.z; h[3] = (half_t)v.w;
        *(half4v*)&p.a16[base] = h;
    }
    {   // weight transpose+convert: 4 tiles of 32x32 per block (1024 tiles total)
        float(*T)[33] = (float(*)[33])smem;
        const int r = tid >> 3, c4 = (tid & 7) * 4;
        #pragma unroll
        for (int t = 0; t < 4; ++t) {
            int g = bid * 4 + t;
            int idx, K, N, tk, tn;
            if (g < 256)      { idx = g >> 7;                 K = 256; N = 512; int j = g & 127; tk = j >> 4; tn = j & 15; }
            else if (g < 768) { int h2 = g - 256; idx = 2 + (h2 >> 8); K = 512; N = 512; int j = h2 & 255; tk = j >> 4; tn = j & 15; }
            else              { int h2 = g - 768; idx = 4 + (h2 >> 7); K = 512; N = 256; int j = h2 & 127; tk = j >> 3; tn = j & 7; }
            const float* src = p.w[idx];
            half_t* dst = p.wt[idx];
            float4 v = *(const float4*)&src[(tk * 32 + r) * N + tn * 32 + c4];
            __syncthreads();   // protect T reuse across iterations
            T[r][c4 + 0] = v.x; T[r][c4 + 1] = v.y; T[r][c4 + 2] = v.z; T[r][c4 + 3] = v.w;
            __syncthreads();
            half4v h;
            h[0] = (half_t)T[c4 + 0][r];
            h[1] = (half_t)T[c4 + 1][r];
            h[2] = (half_t)T[c4 + 2][r];
            h[3] = (half_t)T[c4 + 3][r];
            *(half4v*)&dst[(tn * 32 + r) * K + tk * 32 + c4] = h;
        }
    }
    if (bid < 64) {   // colstats partials (16 rows each)
        const int d = tid, r0 = bid * 16;
        float s = 0.f, s2 = 0.f;
        #pragma unroll
        for (int r = 0; r < 16; ++r) {
            float v = p.b[(r0 + r) * DIM + d];
            s += v; s2 = fmaf(v, v, s2);
        }
        p.part_s[bid * DIM + d] = s;
        p.part_s2[bid * DIM + d] = s2;
    }
    if (bid == 0 && tid == 0) { *p.acc = 0.f; *p.done = 0u; }
    gsync(p.bar + 0);

    // ================= phase 1: layer 0 (K=256 -> N=512) =================
    {
        const int net = bid >> 7, r = bid & 127;
        const int bm = (r >> 3) * 64, bn = (r & 7) * 64;
        gemm_tile(p.a16, net ? p.wt[1] : p.wt[0], net ? p.bias[1] : p.bias[0],
                  net ? (void*)p.h1l : (void*)p.h1m, DIM, HID, bm, bn, true, true, smem);
    }
    gsync(p.bar + 32);

    // ================= phase 2: layer 1 (K=512 -> N=512) =================
    {
        const int net = bid >> 7, r = bid & 127;
        const int bm = (r >> 3) * 64, bn = (r & 7) * 64;
        gemm_tile(net ? p.h1l : p.h1m, net ? p.wt[3] : p.wt[2], net ? p.bias[3] : p.bias[2],
                  net ? (void*)p.h2l : (void*)p.h2m, HID, HID, bm, bn, true, true, smem);
    }
    gsync(p.bar + 64);

    // ================= phase 3: layer 2 (K=512 -> N=256, f32 out) =================
    if (bid < 128) {
        const int net = bid >> 6, r = bid & 63;
        const int bm = (r >> 2) * 64, bn = (r & 3) * 64;
        gemm_tile(net ? p.h2l : p.h2m, net ? p.wt[5] : p.wt[4], net ? p.bias[5] : p.bias[4],
                  net ? (void*)p.lv_raw : (void*)p.mu_raw, HID, DIM, bm, bn, false, false, smem);
    }
    gsync(p.bar + 96);

    // ================= phase 4: loss (64 blocks x 16 rows) =================
    if (bid < 64) {
        float* ebL  = (float*)smem;        // 256
        float* eb2L = ebL + 256;           // 256
        float* bsum = ebL + 512;
        {
            const int d = tid;
            float s = 0.f, s2 = 0.f;
            #pragma unroll 8
            for (int j = 0; j < 64; ++j) {
                s  += p.part_s[j * DIM + d];
                s2 += p.part_s2[j * DIM + d];
            }
            ebL[d]  = s  * (1.f / (float)N_ROWS);
            eb2L[d] = s2 * (1.f / (float)N_ROWS);
        }
        if (tid == 0) *bsum = 0.f;
        __syncthreads();

        const int wave = tid >> 6, lane = tid & 63;
        float wacc = 0.f;
        #pragma unroll
        for (int rr = 0; rr < 4; ++rr) {
            const int i = bid * 16 + wave * 4 + rr;
            float m4[4], l4[4], ss = 0.f;
            #pragma unroll
            for (int t = 0; t < 4; ++t) {
                int d = lane + t * 64;
                m4[t] = p.mu_raw[i * DIM + d];
                l4[t] = p.lv_raw[i * DIM + d];
                ss = fmaf(m4[t], m4[t], ss);
            }
            #pragma unroll
            for (int o = 32; o > 0; o >>= 1) ss += __shfl_xor(ss, o, 64);
            const float inv_norm = 1.f / fmaxf(sqrtf(ss), 1e-12f);
            #pragma unroll
            for (int t = 0; t < 4; ++t) {
                int d = lane + t * 64;
                float mu = m4[t] * inv_norm;
                float lv = tanhf(l4[t]);
                float iv = expf(-lv);
                float diff2 = fmaf(mu, mu, fmaf(-2.f * mu, ebL[d], eb2L[d]));
                wacc += fmaf(diff2, iv, lv);
            }
        }
        #pragma unroll
        for (int o = 32; o > 0; o >>= 1) wacc += __shfl_xor(wacc, o, 64);
        if (lane == 0) atomicAdd(bsum, wacc);
        __syncthreads();
        if (tid == 0) {
            atomicAdd(p.acc, *bsum);
            __threadfence();
            unsigned prev = __hip_atomic_fetch_add(p.done, 1u, __ATOMIC_ACQ_REL, __HIP_MEMORY_SCOPE_AGENT);
            if (prev == 63u) {
                __threadfence();
                float v = __hip_atomic_load(p.acc, __ATOMIC_RELAXED, __HIP_MEMORY_SCOPE_AGENT);
                p.out[0] = v * (1.0f / (float)N_ROWS);
            }
        }
    }
}

extern "C" void kernel_launch(void* const* d_in, const int* in_sizes, int n_in,
                              void* d_out, int out_size, void* d_ws, size_t ws_size,
                              hipStream_t stream) {
    Params p;
    p.a = (const float*)d_in[0];
    p.b = (const float*)d_in[1];
    p.w[0] = (const float*)d_in[2];  p.bias[0] = (const float*)d_in[3];   // mu L0
    p.w[2] = (const float*)d_in[4];  p.bias[2] = (const float*)d_in[5];   // mu L1
    p.w[4] = (const float*)d_in[6];  p.bias[4] = (const float*)d_in[7];   // mu L2
    p.w[1] = (const float*)d_in[8];  p.bias[1] = (const float*)d_in[9];   // lv L0
    p.w[3] = (const float*)d_in[10]; p.bias[3] = (const float*)d_in[11];  // lv L1
    p.w[5] = (const float*)d_in[12]; p.bias[5] = (const float*)d_in[13];  // lv L2

    float* f = (float*)d_ws;
    p.bar    = (unsigned*)f;            // counters at 0,32,64,96
    p.acc    = f + 128;
    p.done   = (unsigned*)(f + 160);
    p.part_s  = f + 256;                // 64*256
    p.part_s2 = p.part_s + 64 * DIM;    // 64*256
    p.mu_raw  = f + 40960;              // 1024*256
    p.lv_raw  = p.mu_raw + N_ROWS * DIM;

    half_t* hb = (half_t*)(p.lv_raw + N_ROWS * DIM);
    p.a16   = hb;                        hb += N_ROWS * DIM;
    p.wt[0] = hb;                        hb += HID * DIM;
    p.wt[1] = hb;                        hb += HID * DIM;
    p.wt[2] = hb;                        hb += HID * HID;
    p.wt[3] = hb;                        hb += HID * HID;
    p.wt[4] = hb;                        hb += DIM * HID;
    p.wt[5] = hb;                        hb += DIM * HID;
    p.h1m   = hb;                        hb += N_ROWS * HID;
    p.h1l   = hb;                        hb += N_ROWS * HID;
    p.h2m   = hb;                        hb += N_ROWS * HID;
    p.h2l   = hb;                        hb += N_ROWS * HID;
    p.out   = (float*)d_out;

    hipMemsetAsync(d_ws, 0, 1024, stream);   // zero barriers + acc + done
    fused_kernel<<<dim3(NB), dim3(NT), 0, stream>>>(p);
}

// Round 5
// 84.140 us; speedup vs baseline: 2.8525x; 2.8525x over previous
//
#include <hip/hip_runtime.h>
#include <hip/hip_fp16.h>

#define N_ROWS 1024
#define DIM 256
#define HID 512

typedef _Float16 half_t;
typedef __attribute__((ext_vector_type(8))) _Float16 half8v;
typedef __attribute__((ext_vector_type(16))) float f32x16;

struct Params {
    const float* a;
    const float* b;
    const float* w[6];      // w0m,w0l,w1m,w1l,w2m,w2l (fp32, K x N)
    const float* bias[6];
    unsigned* flags;        // [32] per-pair handoff flags (zeroed per call)
    float* acc;             // zeroed per call
    unsigned* done;         // zeroed per call
    float* ebsum;           // [256] (zeroed per call)
    float* eb2sum;          // [256]
    float* g_mu;            // [1024*256] f32 raw mu handoff
    half_t* wt[6];          // transposed f16 weights (N x K)
    float* out;
};

// ---------------- prep: weight transpose+convert, colstats ----------------
__global__ __launch_bounds__(256) void prep_kernel(Params p) {
    __shared__ float T[32][33];
    const int y = blockIdx.y, bx = blockIdx.x, tid = threadIdx.x;

    if (y == 6) {           // colstats: 64 blocks x 16 rows
        if (bx >= 64) return;
        const int d = tid, r0 = bx * 16;
        float s = 0.f, s2 = 0.f;
        #pragma unroll
        for (int r = 0; r < 16; ++r) {
            float v = p.b[(r0 + r) * DIM + d];
            s += v; s2 = fmaf(v, v, s2);
        }
        atomicAdd(&p.ebsum[d], s);
        atomicAdd(&p.eb2sum[d], s2);
        return;
    }
    const float* src = p.w[y];
    half_t* dst = p.wt[y];
    const int K = (y < 2) ? DIM : HID;
    const int N = (y < 4) ? HID : DIM;
    const int ltpr = (N == HID) ? 4 : 3;          // log2(N/32)
    const int ntiles = (K >> 5) << ltpr;
    if (bx >= ntiles) return;
    const int tk = bx >> ltpr, tn = bx & ((1 << ltpr) - 1);
    const int r = tid >> 3, c4 = (tid & 7) * 4;
    float4 v = *(const float4*)&src[(tk * 32 + r) * N + tn * 32 + c4];
    T[r][c4 + 0] = v.x; T[r][c4 + 1] = v.y; T[r][c4 + 2] = v.z; T[r][c4 + 3] = v.w;
    __syncthreads();
    half_t h0 = (half_t)T[c4 + 0][r];
    half_t h1 = (half_t)T[c4 + 1][r];
    half_t h2 = (half_t)T[c4 + 2][r];
    half_t h3 = (half_t)T[c4 + 3][r];
    half_t* dp = &dst[(tn * 32 + r) * K + tk * 32 + c4];
    dp[0] = h0; dp[1] = h1; dp[2] = h2; dp[3] = h3;
}

// ---------------- one MLP layer inside the block ----------------
// Xin: LDS [32][520] f16. wt: global N x K f16. BS: LDS staging [NOUT][40].
// MODE 0: relu -> Xout f16 LDS. MODE 1: raw f32 -> global gmu (agent stores).
// MODE 2: raw f32 -> LDS rawout [32][260].
template <int K, int NOUT, int TPW, int MODE>
__device__ __forceinline__ void layer_run(const half_t* __restrict__ wt,
                                          const float* __restrict__ bias,
                                          const half_t* Xin, half_t* Xout,
                                          float* rawout, float* gmu,
                                          half_t* BS) {
    const int tid = threadIdx.x;
    const int wave = tid >> 6, lane = tid & 63;
    const int lr = lane & 31, hi = lane >> 5;
    constexpr int NC = K / 32;
    constexpr int NI = NOUT / 128;
    const int nn = tid >> 2, k8 = (tid & 3) * 8;

    f32x16 acc[TPW];
    #pragma unroll
    for (int t = 0; t < TPW; ++t)
        #pragma unroll
        for (int i = 0; i < 16; ++i) acc[t][i] = 0.f;

    float4 pr[NI];
    #pragma unroll
    for (int i = 0; i < NI; ++i)
        pr[i] = *(const float4*)&wt[(nn + 128 * i) * K + k8];

    for (int kc = 0; kc < NC; ++kc) {
        __syncthreads();                          // previous BS consumers done
        #pragma unroll
        for (int i = 0; i < NI; ++i)
            *(float4*)&BS[(nn + 128 * i) * 40 + k8] = pr[i];
        if (kc + 1 < NC) {
            #pragma unroll
            for (int i = 0; i < NI; ++i)
                pr[i] = *(const float4*)&wt[(nn + 128 * i) * K + (kc + 1) * 32 + k8];
        }
        __syncthreads();                          // BS ready
        half8v av0 = *(const half8v*)&Xin[lr * 520 + kc * 32 + hi * 8];
        half8v av1 = *(const half8v*)&Xin[lr * 520 + kc * 32 + 16 + hi * 8];
        #pragma unroll
        for (int t = 0; t < TPW; ++t) {
            const int wc = wave * (32 * TPW) + t * 32;
            half8v bv0 = *(const half8v*)&BS[(wc + lr) * 40 + hi * 8];
            half8v bv1 = *(const half8v*)&BS[(wc + lr) * 40 + 16 + hi * 8];
            acc[t] = __builtin_amdgcn_mfma_f32_32x32x16_f16(av0, bv0, acc[t], 0, 0, 0);
            acc[t] = __builtin_amdgcn_mfma_f32_32x32x16_f16(av1, bv1, acc[t], 0, 0, 0);
        }
    }
    if (MODE == 2) __syncthreads();               // rawout overlaps BS
    // C/D layout: col = lane&31, row = (reg&3) + 8*(reg>>2) + 4*(lane>>5)
    #pragma unroll
    for (int t = 0; t < TPW; ++t) {
        const int col = wave * (32 * TPW) + t * 32 + lr;
        const float bv = bias[col];
        #pragma unroll
        for (int r = 0; r < 16; ++r) {
            const int row = (r & 3) + 8 * (r >> 2) + 4 * hi;
            float v = acc[t][r] + bv;
            if (MODE == 0) {
                v = fmaxf(v, 0.f);
                Xout[row * 520 + col] = (half_t)v;
            } else if (MODE == 1) {
                __hip_atomic_store(&gmu[row * DIM + col], v, __ATOMIC_RELAXED,
                                   __HIP_MEMORY_SCOPE_AGENT);
            } else {
                rawout[row * 260 + col] = v;
            }
        }
    }
}

// ---------------- main: row-local fused MLP + loss ----------------
__global__ __launch_bounds__(512) void main_kernel(Params p) {
    __shared__ alignas(16) char smem[107520];
    half_t* X1 = (half_t*)smem;                  // [32][520]
    half_t* X2 = (half_t*)(smem + 33280);        // [32][520]
    half_t* BS = (half_t*)(smem + 66560);        // [512][40]
    float* raw = (float*)(smem + 66560);         // [32][260] (after BS dead)
    float* bsum = (float*)(smem + 33280);        // overlaps X2 (dead in loss)

    const int bid = blockIdx.x, tid = threadIdx.x;
    const int net = bid & 1, rg = bid >> 1, R0 = rg * 32;

    // stage a rows -> X1 f16
    {
        const int row = tid >> 4, c16 = (tid & 15) * 16;
        const float* src = &p.a[(R0 + row) * DIM + c16];
        float4 v0 = *(const float4*)(src);
        float4 v1 = *(const float4*)(src + 4);
        float4 v2 = *(const float4*)(src + 8);
        float4 v3 = *(const float4*)(src + 12);
        half8v h0, h1;
        h0[0] = (half_t)v0.x; h0[1] = (half_t)v0.y; h0[2] = (half_t)v0.z; h0[3] = (half_t)v0.w;
        h0[4] = (half_t)v1.x; h0[5] = (half_t)v1.y; h0[6] = (half_t)v1.z; h0[7] = (half_t)v1.w;
        h1[0] = (half_t)v2.x; h1[1] = (half_t)v2.y; h1[2] = (half_t)v2.z; h1[3] = (half_t)v2.w;
        h1[4] = (half_t)v3.x; h1[5] = (half_t)v3.y; h1[6] = (half_t)v3.z; h1[7] = (half_t)v3.w;
        *(half8v*)&X1[row * 520 + c16] = h0;
        *(half8v*)&X1[row * 520 + c16 + 8] = h1;
    }

    layer_run<DIM, HID, 2, 0>(p.wt[0 + net], p.bias[0 + net], X1, X2, nullptr, nullptr, BS);
    layer_run<HID, HID, 2, 0>(p.wt[2 + net], p.bias[2 + net], X2, X1, nullptr, nullptr, BS);

    float* gmu = p.g_mu + R0 * DIM;
    if (net == 0) {
        layer_run<HID, DIM, 1, 1>(p.wt[4], p.bias[4], X1, nullptr, nullptr, gmu, BS);
        __syncthreads();   // compiler emits s_waitcnt vmcnt(0) before barrier: stores drained
        if (tid == 0)
            __hip_atomic_store(&p.flags[rg], 1u, __ATOMIC_RELAXED, __HIP_MEMORY_SCOPE_AGENT);
        return;
    }
    layer_run<HID, DIM, 1, 2>(p.wt[5], p.bias[5], X1, nullptr, raw, nullptr, BS);

    if (tid == 0) {
        *bsum = 0.f;
        while (__hip_atomic_load(&p.flags[rg], __ATOMIC_RELAXED, __HIP_MEMORY_SCOPE_AGENT) == 0u)
            __builtin_amdgcn_s_sleep(1);
        asm volatile("" ::: "memory");
    }
    __syncthreads();

    // loss for rows R0..R0+31
    const int wave = tid >> 6, lane = tid & 63;
    const float invN = 1.0f / (float)N_ROWS;
    float wacc = 0.f;
    #pragma unroll
    for (int rr = 0; rr < 4; ++rr) {
        const int r = wave * 4 + rr;
        float m4[4], l4[4], ss = 0.f;
        #pragma unroll
        for (int t = 0; t < 4; ++t) {
            const int d = lane + t * 64;
            m4[t] = __hip_atomic_load(&gmu[r * DIM + d], __ATOMIC_RELAXED,
                                      __HIP_MEMORY_SCOPE_AGENT);
            l4[t] = raw[r * 260 + d];
            ss = fmaf(m4[t], m4[t], ss);
        }
        #pragma unroll
        for (int o = 32; o > 0; o >>= 1) ss += __shfl_xor(ss, o, 64);
        const float inv_norm = 1.f / fmaxf(sqrtf(ss), 1e-12f);
        #pragma unroll
        for (int t = 0; t < 4; ++t) {
            const int d = lane + t * 64;
            float mu = m4[t] * inv_norm;
            float lv = tanhf(l4[t]);
            float iv = expf(-lv);
            float eb = p.ebsum[d] * invN;
            float eb2 = p.eb2sum[d] * invN;
            float diff2 = fmaf(mu, mu, fmaf(-2.f * mu, eb, eb2));
            wacc += fmaf(diff2, iv, lv);
        }
    }
    #pragma unroll
    for (int o = 32; o > 0; o >>= 1) wacc += __shfl_xor(wacc, o, 64);
    if (lane == 0) atomicAdd(bsum, wacc);
    __syncthreads();
    if (tid == 0) {
        atomicAdd(p.acc, *bsum);
        asm volatile("s_waitcnt vmcnt(0)" ::: "memory");   // add at coherence point
        unsigned prev = __hip_atomic_fetch_add(p.done, 1u, __ATOMIC_RELAXED,
                                               __HIP_MEMORY_SCOPE_AGENT);
        if (prev == 31u) {
            float v = __hip_atomic_load(p.acc, __ATOMIC_RELAXED, __HIP_MEMORY_SCOPE_AGENT);
            p.out[0] = v * (1.0f / (float)N_ROWS);
        }
    }
}

extern "C" void kernel_launch(void* const* d_in, const int* in_sizes, int n_in,
                              void* d_out, int out_size, void* d_ws, size_t ws_size,
                              hipStream_t stream) {
    Params p;
    p.a = (const float*)d_in[0];
    p.b = (const float*)d_in[1];
    p.w[0] = (const float*)d_in[2];  p.bias[0] = (const float*)d_in[3];   // mu L0
    p.w[2] = (const float*)d_in[4];  p.bias[2] = (const float*)d_in[5];   // mu L1
    p.w[4] = (const float*)d_in[6];  p.bias[4] = (const float*)d_in[7];   // mu L2
    p.w[1] = (const float*)d_in[8];  p.bias[1] = (const float*)d_in[9];   // lv L0
    p.w[3] = (const float*)d_in[10]; p.bias[3] = (const float*)d_in[11];  // lv L1
    p.w[5] = (const float*)d_in[12]; p.bias[5] = (const float*)d_in[13];  // lv L2

    float* f = (float*)d_ws;
    p.flags  = (unsigned*)f;            // [0..31]
    p.acc    = f + 32;
    p.done   = (unsigned*)(f + 33);
    p.ebsum  = f + 64;                  // [64..319]
    p.eb2sum = f + 320;                 // [320..575]
    p.g_mu   = f + 1024;                // 1024*256 f32
    half_t* hb = (half_t*)(p.g_mu + N_ROWS * DIM);
    p.wt[0] = hb;  hb += HID * DIM;
    p.wt[1] = hb;  hb += HID * DIM;
    p.wt[2] = hb;  hb += HID * HID;
    p.wt[3] = hb;  hb += HID * HID;
    p.wt[4] = hb;  hb += DIM * HID;
    p.wt[5] = hb;  hb += DIM * HID;
    p.out   = (float*)d_out;

    hipMemsetAsync(d_ws, 0, 2304, stream);   // flags + acc + done + ebsum + eb2sum
    prep_kernel<<<dim3(256, 7), 256, 0, stream>>>(p);
    main_kernel<<<64, 512, 0, stream>>>(p);
}

// Round 6
// 48.654 us; speedup vs baseline: 4.9329x; 1.7293x over previous
//
#include <hip/hip_runtime.h>
#include <hip/hip_fp16.h>

#define N_ROWS 1024
#define DIM 256
#define HID 512

typedef _Float16 half_t;
typedef __attribute__((ext_vector_type(8))) _Float16 half8v;
typedef __attribute__((ext_vector_type(4))) _Float16 half4v;
typedef __attribute__((ext_vector_type(16))) float f32x16;

struct Params {
    const float* a;
    const float* b;
    const float* w[6];      // w0m,w0l,w1m,w1l,w2m,w2l (fp32, K x N)
    const float* bias[6];
    unsigned* c1;           // [32] (net*16+m), target 8
    unsigned* c2;           // [32]
    unsigned* c3;           // [16] (m), target 8
    float* acc;
    unsigned* done;
    float* ebsum;           // [256]
    float* eb2sum;          // [256]
    half_t* a16;            // [1024][256]
    half_t* wt[6];          // transposed f16 weights (N x K)
    half_t* h1[2];          // [1024][512] per net
    half_t* h2[2];          // [1024][512]
    float* raw[2];          // [1024][256] f32 (mu, lv)
    float* out;
};

// ---------------- prep: weight transpose+convert, a16, colstats ----------------
__global__ __launch_bounds__(256) void prep_kernel(Params p) {
    __shared__ float T[32][33];
    const int y = blockIdx.y, bx = blockIdx.x, tid = threadIdx.x;

    if (y == 6) {           // colstats: 64 blocks x 16 rows
        if (bx >= 64) return;
        const int d = tid, r0 = bx * 16;
        float s = 0.f, s2 = 0.f;
        #pragma unroll
        for (int r = 0; r < 16; ++r) {
            float v = p.b[(r0 + r) * DIM + d];
            s += v; s2 = fmaf(v, v, s2);
        }
        atomicAdd(&p.ebsum[d], s);
        atomicAdd(&p.eb2sum[d], s2);
        return;
    }
    if (y == 7) {           // domain_a fp32 -> f16
        int base = bx * 1024 + tid * 4;
        float4 v = *(const float4*)&p.a[base];
        half4v h; h[0] = (half_t)v.x; h[1] = (half_t)v.y; h[2] = (half_t)v.z; h[3] = (half_t)v.w;
        *(half4v*)&p.a16[base] = h;
        return;
    }
    const float* src = p.w[y];
    half_t* dst = p.wt[y];
    const int K = (y < 2) ? DIM : HID;
    const int N = (y < 4) ? HID : DIM;
    const int ltpr = (N == HID) ? 4 : 3;          // log2(N/32)
    const int ntiles = (K >> 5) << ltpr;
    if (bx >= ntiles) return;
    const int tk = bx >> ltpr, tn = bx & ((1 << ltpr) - 1);
    const int r = tid >> 3, c4 = (tid & 7) * 4;
    float4 v = *(const float4*)&src[(tk * 32 + r) * N + tn * 32 + c4];
    T[r][c4 + 0] = v.x; T[r][c4 + 1] = v.y; T[r][c4 + 2] = v.z; T[r][c4 + 3] = v.w;
    __syncthreads();
    half4v h;
    h[0] = (half_t)T[c4 + 0][r];
    h[1] = (half_t)T[c4 + 1][r];
    h[2] = (half_t)T[c4 + 2][r];
    h[3] = (half_t)T[c4 + 3][r];
    *(half4v*)&dst[(tn * 32 + r) * K + tk * 32 + c4] = h;
}

// ---------------- flag sync helpers (proven in round 5) ----------------
__device__ __forceinline__ void flag_add(unsigned* c) {
    __syncthreads();                 // all waves' stores drained (vmcnt(0) before s_barrier)
    if (threadIdx.x == 0)
        __hip_atomic_fetch_add(c, 1u, __ATOMIC_RELAXED, __HIP_MEMORY_SCOPE_AGENT);
}
__device__ __forceinline__ void flag_wait(unsigned* c, unsigned tgt) {
    if (threadIdx.x == 0) {
        while (__hip_atomic_load(c, __ATOMIC_RELAXED, __HIP_MEMORY_SCOPE_AGENT) < tgt)
            __builtin_amdgcn_s_sleep(1);
        asm volatile("" ::: "memory");
    }
    __syncthreads();
}

// ---------------- 64x64 MFMA GEMM tile (round-3 validated) ----------------
// A: M x K f16 row-major (plain cached loads); Wt: N x K f16.
// MODE 0: relu -> f16 agent store. MODE 1: raw f32 agent store.
template <int MODE>
__device__ __forceinline__ void gemm_tile(const half_t* __restrict__ A,
                                          const half_t* __restrict__ Wt,
                                          const float* __restrict__ bias,
                                          void* __restrict__ Cp,
                                          const int K, const int Nout,
                                          const int bm, const int bn,
                                          char* smemraw) {
    typedef half_t(*lds_t)[64][40];
    lds_t As = (lds_t)smemraw;                       // [2][64][40]
    lds_t Bs = (lds_t)(smemraw + 2 * 64 * 40 * 2);

    const int tid = threadIdx.x;
    const int sr = tid >> 2, sg = (tid & 3) * 8;
    const int wave = tid >> 6, lane = tid & 63;
    const int wr = (wave >> 1) * 32, wc = (wave & 1) * 32;
    const int lr = lane & 31, hi = lane >> 5;

    f32x16 acc;
    #pragma unroll
    for (int i = 0; i < 16; ++i) acc[i] = 0.f;

    const half_t* aP = &A[(bm + sr) * K + sg];
    const half_t* bP = &Wt[(bn + sr) * K + sg];
    const int NC = K >> 5;

    float4 aR = *(const float4*)aP;
    float4 bR = *(const float4*)bP;
    *(float4*)&As[0][sr][sg] = aR;
    *(float4*)&Bs[0][sr][sg] = bR;
    __syncthreads();

    for (int c = 0; c < NC; ++c) {
        const int cur = c & 1;
        const bool more = (c + 1 < NC);
        if (more) {
            aR = *(const float4*)(aP + (c + 1) * 32);
            bR = *(const float4*)(bP + (c + 1) * 32);
        }
        half8v av0 = *(const half8v*)&As[cur][wr + lr][hi * 8];
        half8v bv0 = *(const half8v*)&Bs[cur][wc + lr][hi * 8];
        acc = __builtin_amdgcn_mfma_f32_32x32x16_f16(av0, bv0, acc, 0, 0, 0);
        half8v av1 = *(const half8v*)&As[cur][wr + lr][hi * 8 + 16];
        half8v bv1 = *(const half8v*)&Bs[cur][wc + lr][hi * 8 + 16];
        acc = __builtin_amdgcn_mfma_f32_32x32x16_f16(av1, bv1, acc, 0, 0, 0);
        __syncthreads();
        if (more) {
            const int nxt = cur ^ 1;
            *(float4*)&As[nxt][sr][sg] = aR;
            *(float4*)&Bs[nxt][sr][sg] = bR;
            __syncthreads();
        }
    }

    // C/D layout: col = lane&31, row = (reg&3) + 8*(reg>>2) + 4*(lane>>5)
    const int col = bn + wc + lr;
    const float bv = bias[col];
    const int rbase = bm + wr + 4 * hi;
    #pragma unroll
    for (int r = 0; r < 16; ++r) {
        const int row = rbase + (r & 3) + 8 * (r >> 2);
        float v = acc[r] + bv;
        if (MODE == 0) {
            v = fmaxf(v, 0.f);
            union { half_t h; unsigned short u; } cv;
            cv.h = (half_t)v;
            __hip_atomic_store((unsigned short*)Cp + row * Nout + col, cv.u,
                               __ATOMIC_RELAXED, __HIP_MEMORY_SCOPE_AGENT);
        } else {
            __hip_atomic_store((float*)Cp + row * Nout + col, v,
                               __ATOMIC_RELAXED, __HIP_MEMORY_SCOPE_AGENT);
        }
    }
}

// ---------------- fused main: L0 -> L1 -> L2 -> loss, flag-synced ----------------
__global__ void __launch_bounds__(256) main_kernel(Params p) {
    __shared__ alignas(16) char smem[20480];
    const int bid = blockIdx.x, tid = threadIdx.x;
    const int net = bid & 1;
    const int m = (bid >> 1) & 15;
    const int n = bid >> 5;                 // 0..7
    const int bm = m * 64;

    // phase L0: a16[1024x256] @ wt[net][512x256] -> h1[net] (relu)
    gemm_tile<0>(p.a16, p.wt[net], p.bias[net], p.h1[net], DIM, HID, bm, n * 64, smem);
    flag_add(&p.c1[net * 16 + m]);

    // phase L1: h1 @ wt[2+net][512x512] -> h2[net] (relu)
    flag_wait(&p.c1[net * 16 + m], 8);
    gemm_tile<0>(p.h1[net], p.wt[2 + net], p.bias[2 + net], p.h2[net], HID, HID, bm, n * 64, smem);
    flag_add(&p.c2[net * 16 + m]);

    if (n >= 4) return;

    // phase L2: h2 @ wt[4+net][256x512] -> raw[net] f32
    flag_wait(&p.c2[net * 16 + m], 8);
    gemm_tile<1>(p.h2[net], p.wt[4 + net], p.bias[4 + net], p.raw[net], HID, DIM, bm, n * 64, smem);
    flag_add(&p.c3[m]);

    if (bid >= 32 || net) return;

    // phase loss: block handles rows m*64 .. m*64+63
    float* ebL  = (float*)smem;         // 256
    float* eb2L = ebL + 256;            // 256
    float* bsum = ebL + 512;
    if (tid == 0) *bsum = 0.f;
    flag_wait(&p.c3[m], 8);
    const float invN = 1.0f / (float)N_ROWS;
    ebL[tid]  = p.ebsum[tid] * invN;
    eb2L[tid] = p.eb2sum[tid] * invN;
    __syncthreads();

    const float* mu_raw = p.raw[0];
    const float* lv_raw = p.raw[1];
    const int wave = tid >> 6, lane = tid & 63;
    float wacc = 0.f;
    #pragma unroll 4
    for (int rr = 0; rr < 16; ++rr) {
        const int i = m * 64 + rr * 4 + wave;
        float m4[4], l4[4], ss = 0.f;
        #pragma unroll
        for (int t = 0; t < 4; ++t) {
            const int d = lane + t * 64;
            m4[t] = mu_raw[i * DIM + d];
            l4[t] = lv_raw[i * DIM + d];
            ss = fmaf(m4[t], m4[t], ss);
        }
        #pragma unroll
        for (int o = 32; o > 0; o >>= 1) ss += __shfl_xor(ss, o, 64);
        const float inv_norm = 1.f / fmaxf(sqrtf(ss), 1e-12f);
        #pragma unroll
        for (int t = 0; t < 4; ++t) {
            const int d = lane + t * 64;
            float mu = m4[t] * inv_norm;
            float lv = tanhf(l4[t]);
            float iv = expf(-lv);
            float diff2 = fmaf(mu, mu, fmaf(-2.f * mu, ebL[d], eb2L[d]));
            wacc += fmaf(diff2, iv, lv);
        }
    }
    #pragma unroll
    for (int o = 32; o > 0; o >>= 1) wacc += __shfl_xor(wacc, o, 64);
    if (lane == 0) atomicAdd(bsum, wacc);
    __syncthreads();
    if (tid == 0) {
        atomicAdd(p.acc, *bsum);
        asm volatile("s_waitcnt vmcnt(0)" ::: "memory");   // acc add globally performed
        unsigned prev = __hip_atomic_fetch_add(p.done, 1u, __ATOMIC_RELAXED,
                                               __HIP_MEMORY_SCOPE_AGENT);
        if (prev == 15u) {
            float v = __hip_atomic_load(p.acc, __ATOMIC_RELAXED, __HIP_MEMORY_SCOPE_AGENT);
            p.out[0] = v * (1.0f / (float)N_ROWS);
        }
    }
}

extern "C" void kernel_launch(void* const* d_in, const int* in_sizes, int n_in,
                              void* d_out, int out_size, void* d_ws, size_t ws_size,
                              hipStream_t stream) {
    Params p;
    p.a = (const float*)d_in[0];
    p.b = (const float*)d_in[1];
    p.w[0] = (const float*)d_in[2];  p.bias[0] = (const float*)d_in[3];   // mu L0
    p.w[2] = (const float*)d_in[4];  p.bias[2] = (const float*)d_in[5];   // mu L1
    p.w[4] = (const float*)d_in[6];  p.bias[4] = (const float*)d_in[7];   // mu L2
    p.w[1] = (const float*)d_in[8];  p.bias[1] = (const float*)d_in[9];   // lv L0
    p.w[3] = (const float*)d_in[10]; p.bias[3] = (const float*)d_in[11];  // lv L1
    p.w[5] = (const float*)d_in[12]; p.bias[5] = (const float*)d_in[13];  // lv L2

    float* f = (float*)d_ws;
    p.c1     = (unsigned*)f;            // [0..31]
    p.c2     = (unsigned*)(f + 32);     // [32..63]
    p.c3     = (unsigned*)(f + 64);     // [64..79]
    p.acc    = f + 80;
    p.done   = (unsigned*)(f + 81);
    p.ebsum  = f + 128;                 // [128..383]
    p.eb2sum = f + 384;                 // [384..639]
    p.raw[0] = f + 1024;                // mu_raw 1024*256 f32
    p.raw[1] = p.raw[0] + N_ROWS * DIM;

    half_t* hb = (half_t*)(p.raw[1] + N_ROWS * DIM);
    p.a16   = hb;  hb += N_ROWS * DIM;
    p.wt[0] = hb;  hb += HID * DIM;
    p.wt[1] = hb;  hb += HID * DIM;
    p.wt[2] = hb;  hb += HID * HID;
    p.wt[3] = hb;  hb += HID * HID;
    p.wt[4] = hb;  hb += DIM * HID;
    p.wt[5] = hb;  hb += DIM * HID;
    p.h1[0] = hb;  hb += N_ROWS * HID;
    p.h1[1] = hb;  hb += N_ROWS * HID;
    p.h2[0] = hb;  hb += N_ROWS * HID;
    p.h2[1] = hb;  hb += N_ROWS * HID;
    p.out   = (float*)d_out;

    hipMemsetAsync(d_ws, 0, 2560, stream);   // counters + acc + done + ebsum + eb2sum
    prep_kernel<<<dim3(256, 8), 256, 0, stream>>>(p);
    main_kernel<<<256, 256, 0, stream>>>(p);
}

// Round 7
// 44.668 us; speedup vs baseline: 5.3732x; 1.0893x over previous
//
#include <hip/hip_runtime.h>
#include <hip/hip_fp16.h>

#define N_ROWS 1024
#define DIM 256
#define HID 512

typedef _Float16 half_t;
typedef __attribute__((ext_vector_type(8))) _Float16 half8v;
typedef __attribute__((ext_vector_type(16))) float f32x16;

struct Params {
    const float* a;
    const float* b;
    const float* w[6];      // w0m,w0l,w1m,w1l,w2m,w2l (fp32, K x N)
    const float* bias[6];
    unsigned* c1;           // [32] (net*16+m), target 8
    unsigned* c2;           // [32]
    unsigned* c3;           // [16] (m), target 8
    unsigned* cs;           // colstats counter, target 64
    float* acc;
    unsigned* done;         // target 64
    float* part_s;          // [64][256]
    float* part_s2;         // [64][256]
    float* raw[2];          // [1024][256] f32 (mu, lv)
    half_t* h1[2];          // [1024][512] per net
    half_t* h2[2];
    float* out;
};

// ---------------- flag sync (round-6 proven; explicit vmcnt drain added) ----
__device__ __forceinline__ void flag_add(unsigned* c) {
    asm volatile("s_waitcnt vmcnt(0)" ::: "memory");   // our global stores drained
    __syncthreads();
    if (threadIdx.x == 0)
        __hip_atomic_fetch_add(c, 1u, __ATOMIC_RELAXED, __HIP_MEMORY_SCOPE_AGENT);
}
__device__ __forceinline__ void flag_wait(unsigned* c, unsigned tgt) {
    if (threadIdx.x == 0) {
        while (__hip_atomic_load(c, __ATOMIC_RELAXED, __HIP_MEMORY_SCOPE_AGENT) < tgt)
            __builtin_amdgcn_s_sleep(1);
        asm volatile("" ::: "memory");
    }
    __syncthreads();
}

// ---------------- 64x64 MFMA GEMM tile, on-the-fly W transpose ----------------
// Av: M x K (fp32 if AF32 else f16) row-major. W: K x Nout fp32 row-major.
// C = act(A @ W + bias). MODE 0: relu -> f16 agent store; MODE 1: f32 agent store.
template <int K, int AF32, int MODE>
__device__ __forceinline__ void gemm_tile(const void* __restrict__ Av,
                                          const float* __restrict__ W,
                                          const float* __restrict__ bias,
                                          void* __restrict__ Cp,
                                          const int Nout, const int bm, const int bn,
                                          char* smemraw) {
    typedef half_t(*lds_t)[64][40];
    lds_t As = (lds_t)smemraw;                        // [2][64][40]
    lds_t Bs = (lds_t)(smemraw + 2 * 64 * 40 * 2);

    const int tid = threadIdx.x;
    const int wave = tid >> 6, lane = tid & 63;
    const int wr = (wave >> 1) * 32, wc = (wave & 1) * 32;
    const int lr = lane & 31, hi = lane >> 5;

    // A staging map: row sr, k-block skb (8 halves each)
    const int sr = tid >> 2, skb = tid & 3;
    const int adst = (skb ^ ((sr >> 3) & 3)) * 8;     // swizzled half offset
    // W staging map: slots tid, tid+256 -> (wk, wn0)
    const int wk0 = tid >> 4, wn00 = (tid & 15) * 4;
    const int wk1 = (tid + 256) >> 4, wn01 = wn00;

    // fragment read offsets (same swizzle)
    const int ra = wr + lr, rb = wc + lr;
    const int sa = (ra >> 3) & 3, sb = (rb >> 3) & 3;
    const int a0off = (hi ^ sa) * 8, a1off = ((hi + 2) ^ sa) * 8;
    const int b0off = (hi ^ sb) * 8, b1off = ((hi + 2) ^ sb) * 8;

    f32x16 acc;
    #pragma unroll
    for (int i = 0; i < 16; ++i) acc[i] = 0.f;

    const float*  Af = (const float*)Av;
    const half_t* Ah = (const half_t*)Av;
    constexpr int NC = K >> 5;

    float4 aR0, aR1, wR0, wR1;
    // ---- load chunk 0 ----
    if (AF32) {
        aR0 = *(const float4*)&Af[(bm + sr) * K + skb * 8];
        aR1 = *(const float4*)&Af[(bm + sr) * K + skb * 8 + 4];
    } else {
        aR0 = *(const float4*)&Ah[(bm + sr) * K + skb * 8];
    }
    wR0 = *(const float4*)&W[wk0 * Nout + bn + wn00];
    wR1 = *(const float4*)&W[wk1 * Nout + bn + wn01];

    // ---- write chunk 0 ----
    {
        if (AF32) {
            half8v h;
            h[0] = (half_t)aR0.x; h[1] = (half_t)aR0.y; h[2] = (half_t)aR0.z; h[3] = (half_t)aR0.w;
            h[4] = (half_t)aR1.x; h[5] = (half_t)aR1.y; h[6] = (half_t)aR1.z; h[7] = (half_t)aR1.w;
            *(half8v*)&As[0][sr][adst] = h;
        } else {
            *(float4*)&As[0][sr][adst] = aR0;
        }
        #pragma unroll
        for (int s = 0; s < 2; ++s) {
            const int wk = s ? wk1 : wk0, wn0 = s ? wn01 : wn00;
            float4 v = s ? wR1 : wR0;
            #pragma unroll
            for (int j = 0; j < 4; ++j) {
                const int row = wn0 + j;
                const int cidx = (((wk >> 3) ^ ((row >> 3) & 3)) * 8) + (wk & 7);
                float e = (j == 0) ? v.x : (j == 1) ? v.y : (j == 2) ? v.z : v.w;
                Bs[0][row][cidx] = (half_t)e;
            }
        }
    }
    __syncthreads();

    for (int c = 0; c < NC; ++c) {
        const int cur = c & 1;
        const bool more = (c + 1 < NC);
        if (more) {
            const int k0 = (c + 1) << 5;
            if (AF32) {
                aR0 = *(const float4*)&Af[(bm + sr) * K + k0 + skb * 8];
                aR1 = *(const float4*)&Af[(bm + sr) * K + k0 + skb * 8 + 4];
            } else {
                aR0 = *(const float4*)&Ah[(bm + sr) * K + k0 + skb * 8];
            }
            wR0 = *(const float4*)&W[(k0 + wk0) * Nout + bn + wn00];
            wR1 = *(const float4*)&W[(k0 + wk1) * Nout + bn + wn01];
        }
        // compute on buf cur
        half8v av0 = *(const half8v*)&As[cur][ra][a0off];
        half8v bv0 = *(const half8v*)&Bs[cur][rb][b0off];
        acc = __builtin_amdgcn_mfma_f32_32x32x16_f16(av0, bv0, acc, 0, 0, 0);
        half8v av1 = *(const half8v*)&As[cur][ra][a1off];
        half8v bv1 = *(const half8v*)&Bs[cur][rb][b1off];
        acc = __builtin_amdgcn_mfma_f32_32x32x16_f16(av1, bv1, acc, 0, 0, 0);
        __syncthreads();
        if (more) {
            const int nxt = cur ^ 1;
            if (AF32) {
                half8v h;
                h[0] = (half_t)aR0.x; h[1] = (half_t)aR0.y; h[2] = (half_t)aR0.z; h[3] = (half_t)aR0.w;
                h[4] = (half_t)aR1.x; h[5] = (half_t)aR1.y; h[6] = (half_t)aR1.z; h[7] = (half_t)aR1.w;
                *(half8v*)&As[nxt][sr][adst] = h;
            } else {
                *(float4*)&As[nxt][sr][adst] = aR0;
            }
            #pragma unroll
            for (int s = 0; s < 2; ++s) {
                const int wk = s ? wk1 : wk0, wn0 = s ? wn01 : wn00;
                float4 v = s ? wR1 : wR0;
                #pragma unroll
                for (int j = 0; j < 4; ++j) {
                    const int row = wn0 + j;
                    const int cidx = (((wk >> 3) ^ ((row >> 3) & 3)) * 8) + (wk & 7);
                    float e = (j == 0) ? v.x : (j == 1) ? v.y : (j == 2) ? v.z : v.w;
                    Bs[nxt][row][cidx] = (half_t)e;
                }
            }
            __syncthreads();
        }
    }

    // epilogue: C/D layout col = lane&31, row = (reg&3)+8*(reg>>2)+4*(lane>>5)
    const int col = bn + wc + lr;
    const float bv = bias[col];
    const int rbase = bm + wr + 4 * hi;
    #pragma unroll
    for (int r = 0; r < 16; ++r) {
        const int row = rbase + (r & 3) + 8 * (r >> 2);
        float v = acc[r] + bv;
        if (MODE == 0) {
            v = fmaxf(v, 0.f);
            union { half_t h; unsigned short u; } cv;
            cv.h = (half_t)v;
            __hip_atomic_store((unsigned short*)Cp + row * Nout + col, cv.u,
                               __ATOMIC_RELAXED, __HIP_MEMORY_SCOPE_AGENT);
        } else {
            __hip_atomic_store((float*)Cp + row * Nout + col, v,
                               __ATOMIC_RELAXED, __HIP_MEMORY_SCOPE_AGENT);
        }
    }
}

// ---------------- single fused kernel ----------------
__global__ void __launch_bounds__(256) fused_kernel(Params p) {
    __shared__ alignas(16) char smem[20480];
    const int bid = blockIdx.x, tid = threadIdx.x;
    const int net = bid & 1;
    const int m = (bid >> 1) & 15;
    const int n = bid >> 5;                 // 0..7
    const int bm = m * 64;

    // ---- L0: a[1024x256] @ w[net] -> h1[net] (relu), fp32 A on the fly ----
    gemm_tile<DIM, 1, 0>(p.a, p.w[net], p.bias[net], p.h1[net], HID, bm, n * 64, smem);
    flag_add(&p.c1[net * 16 + m]);

    // ---- colstats partials on otherwise-waiting blocks (net==1, n>=4) ----
    if (net == 1 && n >= 4) {
        const int idx = m * 4 + (n - 4);    // 0..63
        const int r0 = idx * 16, d = tid;
        float s = 0.f, s2 = 0.f;
        #pragma unroll
        for (int r = 0; r < 16; ++r) {
            float v = p.b[(r0 + r) * DIM + d];
            s += v; s2 = fmaf(v, v, s2);
        }
        __hip_atomic_store(&p.part_s[idx * DIM + d], s, __ATOMIC_RELAXED,
                           __HIP_MEMORY_SCOPE_AGENT);
        __hip_atomic_store(&p.part_s2[idx * DIM + d], s2, __ATOMIC_RELAXED,
                           __HIP_MEMORY_SCOPE_AGENT);
        flag_add(p.cs);
    }

    // ---- L1: h1 @ w[2+net] -> h2[net] (relu) ----
    flag_wait(&p.c1[net * 16 + m], 8);
    gemm_tile<HID, 0, 0>(p.h1[net], p.w[2 + net], p.bias[2 + net], p.h2[net], HID, bm, n * 64, smem);
    flag_add(&p.c2[net * 16 + m]);

    // ---- L2 (n<4): h2 @ w[4+net] -> raw[net] f32 ----
    if (n < 4) {
        flag_wait(&p.c2[net * 16 + m], 8);
        gemm_tile<HID, 0, 1>(p.h2[net], p.w[4 + net], p.bias[4 + net], p.raw[net], DIM, bm, n * 64, smem);
        flag_add(&p.c3[m]);
    }

    // ---- loss (net==0, n>=4): 64 blocks x 16 rows ----
    if (net == 0 && n >= 4) {
        const int q = n - 4;
        flag_wait(p.cs, 64);
        flag_wait(&p.c3[m], 8);

        float* ebL  = (float*)smem;         // 256
        float* eb2L = ebL + 256;            // 256
        float* bsum = ebL + 512;
        {
            const int d = tid;
            float s = 0.f, s2 = 0.f;
            #pragma unroll 8
            for (int j = 0; j < 64; ++j) {
                s  += p.part_s[j * DIM + d];
                s2 += p.part_s2[j * DIM + d];
            }
            ebL[d]  = s  * (1.f / (float)N_ROWS);
            eb2L[d] = s2 * (1.f / (float)N_ROWS);
        }
        if (tid == 0) *bsum = 0.f;
        __syncthreads();

        const float* mu_raw = p.raw[0];
        const float* lv_raw = p.raw[1];
        const int wave = tid >> 6, lane = tid & 63;
        const int rbase = m * 64 + q * 16;
        float wacc = 0.f;
        #pragma unroll
        for (int rr = 0; rr < 4; ++rr) {
            const int i = rbase + wave * 4 + rr;
            float m4[4], l4[4], ss = 0.f;
            #pragma unroll
            for (int t = 0; t < 4; ++t) {
                const int d = lane + t * 64;
                m4[t] = mu_raw[i * DIM + d];
                l4[t] = lv_raw[i * DIM + d];
                ss = fmaf(m4[t], m4[t], ss);
            }
            #pragma unroll
            for (int o = 32; o > 0; o >>= 1) ss += __shfl_xor(ss, o, 64);
            const float inv_norm = 1.f / fmaxf(sqrtf(ss), 1e-12f);
            #pragma unroll
            for (int t = 0; t < 4; ++t) {
                const int d = lane + t * 64;
                float mu = m4[t] * inv_norm;
                float lv = tanhf(l4[t]);
                float iv = expf(-lv);
                float diff2 = fmaf(mu, mu, fmaf(-2.f * mu, ebL[d], eb2L[d]));
                wacc += fmaf(diff2, iv, lv);
            }
        }
        #pragma unroll
        for (int o = 32; o > 0; o >>= 1) wacc += __shfl_xor(wacc, o, 64);
        if (lane == 0) atomicAdd(bsum, wacc);
        __syncthreads();
        if (tid == 0) {
            atomicAdd(p.acc, *bsum);
            asm volatile("s_waitcnt vmcnt(0)" ::: "memory");
            unsigned prev = __hip_atomic_fetch_add(p.done, 1u, __ATOMIC_RELAXED,
                                                   __HIP_MEMORY_SCOPE_AGENT);
            if (prev == 63u) {
                float v = __hip_atomic_load(p.acc, __ATOMIC_RELAXED, __HIP_MEMORY_SCOPE_AGENT);
                p.out[0] = v * (1.0f / (float)N_ROWS);
            }
        }
    }
}

extern "C" void kernel_launch(void* const* d_in, const int* in_sizes, int n_in,
                              void* d_out, int out_size, void* d_ws, size_t ws_size,
                              hipStream_t stream) {
    Params p;
    p.a = (const float*)d_in[0];
    p.b = (const float*)d_in[1];
    p.w[0] = (const float*)d_in[2];  p.bias[0] = (const float*)d_in[3];   // mu L0
    p.w[2] = (const float*)d_in[4];  p.bias[2] = (const float*)d_in[5];   // mu L1
    p.w[4] = (const float*)d_in[6];  p.bias[4] = (const float*)d_in[7];   // mu L2
    p.w[1] = (const float*)d_in[8];  p.bias[1] = (const float*)d_in[9];   // lv L0
    p.w[3] = (const float*)d_in[10]; p.bias[3] = (const float*)d_in[11];  // lv L1
    p.w[5] = (const float*)d_in[12]; p.bias[5] = (const float*)d_in[13];  // lv L2

    float* f = (float*)d_ws;
    p.c1   = (unsigned*)f;              // [0..31]
    p.c2   = (unsigned*)(f + 32);       // [32..63]
    p.c3   = (unsigned*)(f + 64);       // [64..79]
    p.cs   = (unsigned*)(f + 80);
    p.acc  = f + 81;
    p.done = (unsigned*)(f + 82);
    p.part_s  = f + 128;                // 64*256
    p.part_s2 = p.part_s + 64 * DIM;    // 64*256
    p.raw[0]  = p.part_s2 + 64 * DIM;   // 1024*256
    p.raw[1]  = p.raw[0] + N_ROWS * DIM;
    half_t* hb = (half_t*)(p.raw[1] + N_ROWS * DIM);
    p.h1[0] = hb;  hb += N_ROWS * HID;
    p.h1[1] = hb;  hb += N_ROWS * HID;
    p.h2[0] = hb;  hb += N_ROWS * HID;
    p.h2[1] = hb;  hb += N_ROWS * HID;
    p.out = (float*)d_out;

    hipMemsetAsync(d_ws, 0, 512, stream);   // counters + acc + done
    fused_kernel<<<256, 256, 0, stream>>>(p);
}

// Round 8
// 37.239 us; speedup vs baseline: 6.4451x; 1.1995x over previous
//
#include <hip/hip_runtime.h>
#include <hip/hip_fp16.h>

#define N_ROWS 1024
#define DIM 256
#define HID 512

typedef _Float16 half_t;
typedef __attribute__((ext_vector_type(8))) _Float16 half8v;
typedef __attribute__((ext_vector_type(16))) float f32x16;

#define WS_CH 2560   // halves per W chunk [64][40]
#define AS_CH 2560   // halves per A buffer [64][40]

struct Params {
    const float* a;
    const float* b;
    const float* w[6];      // w0m,w0l,w1m,w1l,w2m,w2l (fp32, K x N)
    const float* bias[6];
    unsigned* c1;           // [32] (net*16+m), target 8
    unsigned* c2;           // [32]
    unsigned* c3;           // [16] (m), target 8
    unsigned* cs;           // colstats counter, target 64
    float* acc;
    unsigned* done;         // target 64
    float* part_s;          // [64][256]
    float* part_s2;         // [64][256]
    float* raw[2];          // [1024][256] f32 (mu, lv)
    half_t* h1[2];          // [1024][512] per net
    half_t* h2[2];
    float* out;
};

// ---------------- flag sync (round-6/7 proven) ----------------
__device__ __forceinline__ void flag_add(unsigned* c) {
    asm volatile("s_waitcnt vmcnt(0)" ::: "memory");
    __syncthreads();
    if (threadIdx.x == 0)
        __hip_atomic_fetch_add(c, 1u, __ATOMIC_RELAXED, __HIP_MEMORY_SCOPE_AGENT);
}
__device__ __forceinline__ void flag_wait(unsigned* c, unsigned tgt) {
    if (threadIdx.x == 0) {
        while (__hip_atomic_load(c, __ATOMIC_RELAXED, __HIP_MEMORY_SCOPE_AGENT) < tgt)
            __builtin_amdgcn_s_sleep(1);
        asm volatile("" ::: "memory");
    }
    __syncthreads();
}

// ---------------- stage full W panel (K x 64 cols) -> Ws transposed f16 ----------------
// No barriers inside: caller's flag_wait/prologue barrier publishes it.
template <int K>
__device__ __forceinline__ void stage_W(const float* __restrict__ W, const int Nout,
                                        const int bn, half_t* __restrict__ Ws) {
    const int tid = threadIdx.x;
    const int wk0 = tid >> 4, wn0 = (tid & 15) * 4;
    #pragma unroll 2
    for (int c = 0; c < K / 32; ++c) {
        float4 v0 = *(const float4*)&W[(c * 32 + wk0) * Nout + bn + wn0];
        float4 v1 = *(const float4*)&W[(c * 32 + wk0 + 16) * Nout + bn + wn0];
        half_t* dst = Ws + c * WS_CH;
        #pragma unroll
        for (int s = 0; s < 2; ++s) {
            const int wk = wk0 + s * 16;
            float4 v = s ? v1 : v0;
            #pragma unroll
            for (int j = 0; j < 4; ++j) {
                const int row = wn0 + j;
                const int cidx = (((wk >> 3) ^ ((row >> 3) & 3)) * 8) + (wk & 7);
                float e = (j == 0) ? v.x : (j == 1) ? v.y : (j == 2) ? v.z : v.w;
                dst[row * 40 + cidx] = (half_t)e;
            }
        }
    }
}

// ---------------- GEMM phase: W resident in LDS, A triple-buffered ----------------
// Av: M x K (fp32 if AF32 else f16) row-major. C = act(A @ W + bias).
// MODE 0: relu -> f16 agent store; MODE 1: f32 agent store.
template <int K, int AF32, int MODE>
__device__ __forceinline__ void gemm_phase(const void* __restrict__ Av,
                                           const float* __restrict__ bias,
                                           void* __restrict__ Cp,
                                           const int Nout, const int bm, const int bn,
                                           const half_t* __restrict__ Ws,
                                           half_t* __restrict__ As) {
    const int tid = threadIdx.x;
    const int wave = tid >> 6, lane = tid & 63;
    const int wr = (wave >> 1) * 32, wc = (wave & 1) * 32;
    const int lr = lane & 31, hi = lane >> 5;
    const int sr = tid >> 2, skb = tid & 3;
    const int adst = (skb ^ ((sr >> 3) & 3)) * 8;
    const int ra = wr + lr, rb = wc + lr;
    const int sa = (ra >> 3) & 3, sb = (rb >> 3) & 3;
    const int a0off = (hi ^ sa) * 8, a1off = ((hi + 2) ^ sa) * 8;
    const int b0off = (hi ^ sb) * 8, b1off = ((hi + 2) ^ sb) * 8;
    constexpr int NC = K >> 5;

    const float* Af = (const float*)Av;
    const half_t* Ah = (const half_t*)Av;

    f32x16 acc;
    #pragma unroll
    for (int i = 0; i < 16; ++i) acc[i] = 0.f;

    float4 r0a, r0b, r1a, r1b;   // 2 slots (chunk parity); AF32 uses a+b
    #define LOAD_A(c, xa, xb)                                                   \
        do {                                                                    \
            if (AF32) {                                                         \
                xa = *(const float4*)&Af[(bm + sr) * K + (c) * 32 + skb * 8];   \
                xb = *(const float4*)&Af[(bm + sr) * K + (c) * 32 + skb * 8 + 4]; \
            } else {                                                            \
                xa = *(const float4*)&Ah[(bm + sr) * K + (c) * 32 + skb * 8];   \
            }                                                                   \
        } while (0)
    #define WRITE_A(buf, xa, xb)                                                \
        do {                                                                    \
            half_t* d = As + (buf) * AS_CH + sr * 40 + adst;                    \
            if (AF32) {                                                         \
                half8v h;                                                       \
                h[0] = (half_t)xa.x; h[1] = (half_t)xa.y;                       \
                h[2] = (half_t)xa.z; h[3] = (half_t)xa.w;                       \
                h[4] = (half_t)xb.x; h[5] = (half_t)xb.y;                       \
                h[6] = (half_t)xb.z; h[7] = (half_t)xb.w;                       \
                *(half8v*)d = h;                                                \
            } else {                                                            \
                *(float4*)d = xa;                                               \
            }                                                                   \
        } while (0)

    // prologue: slots hold ch(c+1), ch(c+2) at iter-c entry (slot = chunk&1)
    LOAD_A(0, r0a, r0b);
    LOAD_A(1, r1a, r1b);
    WRITE_A(0, r0a, r0b);
    if (NC > 2) LOAD_A(2, r0a, r0b);

    for (int c = 0; c < NC; ++c) {
        const int w = c + 1;
        if (w < NC) {
            if (w & 1) { WRITE_A(w % 3, r1a, r1b); }
            else       { WRITE_A(w % 3, r0a, r0b); }
        }
        const int fch = c + 3;
        if (fch < NC) {
            if (fch & 1) { LOAD_A(fch, r1a, r1b); }
            else         { LOAD_A(fch, r0a, r0b); }
        }
        __syncthreads();
        const half_t* ab = As + (c % 3) * AS_CH;
        const half_t* wb = Ws + c * WS_CH;
        half8v av0 = *(const half8v*)&ab[ra * 40 + a0off];
        half8v bv0 = *(const half8v*)&wb[rb * 40 + b0off];
        acc = __builtin_amdgcn_mfma_f32_32x32x16_f16(av0, bv0, acc, 0, 0, 0);
        half8v av1 = *(const half8v*)&ab[ra * 40 + a1off];
        half8v bv1 = *(const half8v*)&wb[rb * 40 + b1off];
        acc = __builtin_amdgcn_mfma_f32_32x32x16_f16(av1, bv1, acc, 0, 0, 0);
    }
    #undef LOAD_A
    #undef WRITE_A

    // epilogue: C/D layout col = lane&31, row = (reg&3)+8*(reg>>2)+4*(lane>>5)
    const int col = bn + wc + lr;
    const float bv = bias[col];
    const int rbase = bm + wr + 4 * hi;
    #pragma unroll
    for (int r = 0; r < 16; ++r) {
        const int row = rbase + (r & 3) + 8 * (r >> 2);
        float v = acc[r] + bv;
        if (MODE == 0) {
            v = fmaxf(v, 0.f);
            union { half_t h; unsigned short u; } cv;
            cv.h = (half_t)v;
            __hip_atomic_store((unsigned short*)Cp + row * Nout + col, cv.u,
                               __ATOMIC_RELAXED, __HIP_MEMORY_SCOPE_AGENT);
        } else {
            __hip_atomic_store((float*)Cp + row * Nout + col, v,
                               __ATOMIC_RELAXED, __HIP_MEMORY_SCOPE_AGENT);
        }
    }
}

// ---------------- single fused kernel ----------------
__global__ void __launch_bounds__(256) fused_kernel(Params p) {
    __shared__ alignas(16) char smem[98304];        // Ws 81920B + As 15360B
    half_t* Ws = (half_t*)smem;
    half_t* As = (half_t*)(smem + 81920);

    const int bid = blockIdx.x, tid = threadIdx.x;
    const int net = bid & 1;
    const int m = (bid >> 1) & 15;
    const int n = bid >> 5;                 // 0..7
    const int bm = m * 64;

    // ---- L0: a[1024x256] @ w[net] -> h1[net] (relu) ----
    stage_W<DIM>(p.w[net], HID, n * 64, Ws);
    __syncthreads();                        // publish W0 panel
    gemm_phase<DIM, 1, 0>(p.a, p.bias[net], p.h1[net], HID, bm, n * 64, Ws, As);
    flag_add(&p.c1[net * 16 + m]);

    // ---- colstats partials in sync shadow (net==1, n>=4) ----
    if (net == 1 && n >= 4) {
        const int idx = m * 4 + (n - 4);    // 0..63
        const int r0 = idx * 16, d = tid;
        float s = 0.f, s2 = 0.f;
        #pragma unroll
        for (int r = 0; r < 16; ++r) {
            float v = p.b[(r0 + r) * DIM + d];
            s += v; s2 = fmaf(v, v, s2);
        }
        __hip_atomic_store(&p.part_s[idx * DIM + d], s, __ATOMIC_RELAXED,
                           __HIP_MEMORY_SCOPE_AGENT);
        __hip_atomic_store(&p.part_s2[idx * DIM + d], s2, __ATOMIC_RELAXED,
                           __HIP_MEMORY_SCOPE_AGENT);
        flag_add(p.cs);
    }

    // ---- L1: h1 @ w[2+net] -> h2[net] (relu); W staged before the wait ----
    stage_W<HID>(p.w[2 + net], HID, n * 64, Ws);
    flag_wait(&p.c1[net * 16 + m], 8);      // barrier publishes W1 panel too
    gemm_phase<HID, 0, 0>(p.h1[net], p.bias[2 + net], p.h2[net], HID, bm, n * 64, Ws, As);
    flag_add(&p.c2[net * 16 + m]);

    // ---- L2 (n<4): h2 @ w[4+net] -> raw[net] f32 ----
    if (n < 4) {
        stage_W<HID>(p.w[4 + net], DIM, n * 64, Ws);
        flag_wait(&p.c2[net * 16 + m], 8);
        gemm_phase<HID, 0, 1>(p.h2[net], p.bias[4 + net], p.raw[net], DIM, bm, n * 64, Ws, As);
        flag_add(&p.c3[m]);
    }

    // ---- loss (net==0, n>=4): 64 blocks x 16 rows ----
    if (net == 0 && n >= 4) {
        const int q = n - 4;
        flag_wait(p.cs, 64);
        flag_wait(&p.c3[m], 8);

        float* ebL  = (float*)smem;         // 256
        float* eb2L = ebL + 256;            // 256
        float* bsum = ebL + 512;
        {
            const int d = tid;
            float s = 0.f, s2 = 0.f;
            #pragma unroll 8
            for (int j = 0; j < 64; ++j) {
                s  += p.part_s[j * DIM + d];
                s2 += p.part_s2[j * DIM + d];
            }
            ebL[d]  = s  * (1.f / (float)N_ROWS);
            eb2L[d] = s2 * (1.f / (float)N_ROWS);
        }
        if (tid == 0) *bsum = 0.f;
        __syncthreads();

        const float* mu_raw = p.raw[0];
        const float* lv_raw = p.raw[1];
        const int wave = tid >> 6, lane = tid & 63;
        const int rbase = m * 64 + q * 16;
        float wacc = 0.f;
        #pragma unroll
        for (int rr = 0; rr < 4; ++rr) {
            const int i = rbase + wave * 4 + rr;
            float m4[4], l4[4], ss = 0.f;
            #pragma unroll
            for (int t = 0; t < 4; ++t) {
                const int d = lane + t * 64;
                m4[t] = mu_raw[i * DIM + d];
                l4[t] = lv_raw[i * DIM + d];
                ss = fmaf(m4[t], m4[t], ss);
            }
            #pragma unroll
            for (int o = 32; o > 0; o >>= 1) ss += __shfl_xor(ss, o, 64);
            const float inv_norm = 1.f / fmaxf(sqrtf(ss), 1e-12f);
            #pragma unroll
            for (int t = 0; t < 4; ++t) {
                const int d = lane + t * 64;
                float mu = m4[t] * inv_norm;
                float lv = tanhf(l4[t]);
                float iv = expf(-lv);
                float diff2 = fmaf(mu, mu, fmaf(-2.f * mu, ebL[d], eb2L[d]));
                wacc += fmaf(diff2, iv, lv);
            }
        }
        #pragma unroll
        for (int o = 32; o > 0; o >>= 1) wacc += __shfl_xor(wacc, o, 64);
        if (lane == 0) atomicAdd(bsum, wacc);
        __syncthreads();
        if (tid == 0) {
            atomicAdd(p.acc, *bsum);
            asm volatile("s_waitcnt vmcnt(0)" ::: "memory");
            unsigned prev = __hip_atomic_fetch_add(p.done, 1u, __ATOMIC_RELAXED,
                                                   __HIP_MEMORY_SCOPE_AGENT);
            if (prev == 63u) {
                float v = __hip_atomic_load(p.acc, __ATOMIC_RELAXED, __HIP_MEMORY_SCOPE_AGENT);
                p.out[0] = v * (1.0f / (float)N_ROWS);
            }
        }
    }
}

extern "C" void kernel_launch(void* const* d_in, const int* in_sizes, int n_in,
                              void* d_out, int out_size, void* d_ws, size_t ws_size,
                              hipStream_t stream) {
    Params p;
    p.a = (const float*)d_in[0];
    p.b = (const float*)d_in[1];
    p.w[0] = (const float*)d_in[2];  p.bias[0] = (const float*)d_in[3];   // mu L0
    p.w[2] = (const float*)d_in[4];  p.bias[2] = (const float*)d_in[5];   // mu L1
    p.w[4] = (const float*)d_in[6];  p.bias[4] = (const float*)d_in[7];   // mu L2
    p.w[1] = (const float*)d_in[8];  p.bias[1] = (const float*)d_in[9];   // lv L0
    p.w[3] = (const float*)d_in[10]; p.bias[3] = (const float*)d_in[11];  // lv L1
    p.w[5] = (const float*)d_in[12]; p.bias[5] = (const float*)d_in[13];  // lv L2

    float* f = (float*)d_ws;
    p.c1   = (unsigned*)f;              // [0..31]
    p.c2   = (unsigned*)(f + 32);       // [32..63]
    p.c3   = (unsigned*)(f + 64);       // [64..79]
    p.cs   = (unsigned*)(f + 80);
    p.acc  = f + 81;
    p.done = (unsigned*)(f + 82);
    p.part_s  = f + 128;                // 64*256
    p.part_s2 = p.part_s + 64 * DIM;    // 64*256
    p.raw[0]  = p.part_s2 + 64 * DIM;   // 1024*256
    p.raw[1]  = p.raw[0] + N_ROWS * DIM;
    half_t* hb = (half_t*)(p.raw[1] + N_ROWS * DIM);
    p.h1[0] = hb;  hb += N_ROWS * HID;
    p.h1[1] = hb;  hb += N_ROWS * HID;
    p.h2[0] = hb;  hb += N_ROWS * HID;
    p.h2[1] = hb;  hb += N_ROWS * HID;
    p.out = (float*)d_out;

    hipMemsetAsync(d_ws, 0, 512, stream);   // counters + acc + done
    fused_kernel<<<256, 256, 0, stream>>>(p);
}